// Round 4
// baseline (124.578 us; speedup 1.0000x reference)
//
#include <hip/hip_runtime.h>
#include <hip/hip_fp16.h>
#include <math.h>

#define N_RELS 10
#define N_HID 64

typedef float f4_t __attribute__((ext_vector_type(4)));

// ---------------- Kernel 1: h fp32 -> fp16 (RNE) into workspace ----------------
// Nontemporal reads of h (fp32 never reused) so L2 keeps the written fp16 lines
// warm for the gather kernel. 16 floats per thread per iteration.
__global__ __launch_bounds__(256) void cvt_fp16_kernel(
    const float* __restrict__ h,
    unsigned short* __restrict__ hh,
    long n)  // n = total floats, multiple of 16
{
    long i = (long)blockIdx.x * blockDim.x + threadIdx.x;
    long stride = (long)gridDim.x * blockDim.x;
    const f4_t* __restrict__ h4 = reinterpret_cast<const f4_t*>(h);
    uint4* __restrict__ o4 = reinterpret_cast<uint4*>(hh);
    long n16 = n >> 4;
    for (long k = i; k < n16; k += stride) {
        f4_t a = __builtin_nontemporal_load(&h4[4 * k]);
        f4_t b = __builtin_nontemporal_load(&h4[4 * k + 1]);
        f4_t c = __builtin_nontemporal_load(&h4[4 * k + 2]);
        f4_t d = __builtin_nontemporal_load(&h4[4 * k + 3]);
        __half2 p0 = __floats2half2_rn(a.x, a.y);
        __half2 p1 = __floats2half2_rn(a.z, a.w);
        __half2 p2 = __floats2half2_rn(b.x, b.y);
        __half2 p3 = __floats2half2_rn(b.z, b.w);
        __half2 q0 = __floats2half2_rn(c.x, c.y);
        __half2 q1 = __floats2half2_rn(c.z, c.w);
        __half2 q2 = __floats2half2_rn(d.x, d.y);
        __half2 q3 = __floats2half2_rn(d.z, d.w);
        uint4 o0, o1;
        o0.x = *reinterpret_cast<unsigned int*>(&p0);
        o0.y = *reinterpret_cast<unsigned int*>(&p1);
        o0.z = *reinterpret_cast<unsigned int*>(&p2);
        o0.w = *reinterpret_cast<unsigned int*>(&p3);
        o1.x = *reinterpret_cast<unsigned int*>(&q0);
        o1.y = *reinterpret_cast<unsigned int*>(&q1);
        o1.z = *reinterpret_cast<unsigned int*>(&q2);
        o1.w = *reinterpret_cast<unsigned int*>(&q3);
        o4[2 * k] = o0;
        o4[2 * k + 1] = o1;
    }
}

// ---------------- Kernel 2: gather fp16 rows, dot, sigmoid ----------------
// 8 lanes per edge: lane sub holds dims [sub*8, sub*8+8) as one uint4 (8 halves).
#define EPG 4
__global__ __launch_bounds__(256) void distmult_fp16_kernel(
    const unsigned short* __restrict__ hh,   // [N, 64] fp16
    const float* __restrict__ W,
    const int* __restrict__ src_idx,
    const int* __restrict__ dst_idx,
    const int* __restrict__ rel_idx,
    float* __restrict__ out,
    int n_edges)
{
    __shared__ float Wl[N_RELS * N_HID];
    for (int i = threadIdx.x; i < N_RELS * (N_HID / 4); i += blockDim.x) {
        reinterpret_cast<float4*>(Wl)[i] = reinterpret_cast<const float4*>(W)[i];
    }
    __syncthreads();

    const int sub = threadIdx.x & 7;          // lane within 8-lane edge group
    const int group = threadIdx.x >> 3;       // 32 groups per 256-thr block
    const int groups_per_block = blockDim.x >> 3;
    const long stride = (long)gridDim.x * groups_per_block * EPG;
    const uint4* __restrict__ h8 = reinterpret_cast<const uint4*>(hh); // 8 uint4 per row

    for (long base = ((long)blockIdx.x * groups_per_block + group) * EPG;
         base < n_edges; base += stride) {

        float p[EPG];

        if (base + EPG <= n_edges) {
            const int4 s4 = *reinterpret_cast<const int4*>(&src_idx[base]);
            const int4 d4 = *reinterpret_cast<const int4*>(&dst_idx[base]);
            const int4 r4 = *reinterpret_cast<const int4*>(&rel_idx[base]);

            // 8 independent 16B gathers in flight (4 src rows + 4 dst rows).
            const uint4 u0 = h8[(long)s4.x * 8 + sub];
            const uint4 u1 = h8[(long)s4.y * 8 + sub];
            const uint4 u2 = h8[(long)s4.z * 8 + sub];
            const uint4 u3 = h8[(long)s4.w * 8 + sub];
            const uint4 v0 = h8[(long)d4.x * 8 + sub];
            const uint4 v1 = h8[(long)d4.y * 8 + sub];
            const uint4 v2 = h8[(long)d4.z * 8 + sub];
            const uint4 v3 = h8[(long)d4.w * 8 + sub];

            const int rr[EPG] = {r4.x, r4.y, r4.z, r4.w};
            const uint4 uu[EPG] = {u0, u1, u2, u3};
            const uint4 vv[EPG] = {v0, v1, v2, v3};

            #pragma unroll
            for (int k = 0; k < EPG; ++k) {
                const float* wp = &Wl[rr[k] * N_HID + sub * 8];
                const __half2* up = reinterpret_cast<const __half2*>(&uu[k]);
                const __half2* vp = reinterpret_cast<const __half2*>(&vv[k]);
                float acc = 0.0f;
                #pragma unroll
                for (int j = 0; j < 4; ++j) {
                    float2 uf = __half22float2(up[j]);
                    float2 vf = __half22float2(vp[j]);
                    acc += uf.x * wp[2 * j] * vf.x;
                    acc += uf.y * wp[2 * j + 1] * vf.y;
                }
                p[k] = acc;
            }
        } else {
            #pragma unroll
            for (int k = 0; k < EPG; ++k) {
                long e = base + k;
                if (e < n_edges) {
                    int s = src_idx[e], d = dst_idx[e], r = rel_idx[e];
                    uint4 u = h8[(long)s * 8 + sub];
                    uint4 v = h8[(long)d * 8 + sub];
                    const float* wp = &Wl[r * N_HID + sub * 8];
                    const __half2* up = reinterpret_cast<const __half2*>(&u);
                    const __half2* vp = reinterpret_cast<const __half2*>(&v);
                    float acc = 0.0f;
                    #pragma unroll
                    for (int j = 0; j < 4; ++j) {
                        float2 uf = __half22float2(up[j]);
                        float2 vf = __half22float2(vp[j]);
                        acc += uf.x * wp[2 * j] * vf.x;
                        acc += uf.y * wp[2 * j + 1] * vf.y;
                    }
                    p[k] = acc;
                } else {
                    p[k] = 0.0f;
                }
            }
        }

        // Reduce across the 8-lane group (masks stay within the group).
        #pragma unroll
        for (int k = 0; k < EPG; ++k) {
            p[k] += __shfl_xor(p[k], 1, 64);
            p[k] += __shfl_xor(p[k], 2, 64);
            p[k] += __shfl_xor(p[k], 4, 64);
        }

        // Lanes 0..3 write 4 adjacent edges; out is never re-read -> nontemporal.
        if (sub < EPG) {
            long e = base + sub;
            if (e < n_edges) {
                float pv = p[sub];
                float sv = 1.0f / (1.0f + __expf(-pv));
                __builtin_nontemporal_store(sv, &out[e]);
            }
        }
    }
}

// ---------------- Fallback fp32 kernel (if workspace too small) ----------------
__global__ __launch_bounds__(256) void distmult_fp32_kernel(
    const float* __restrict__ h,
    const float* __restrict__ W,
    const int* __restrict__ src_idx,
    const int* __restrict__ dst_idx,
    const int* __restrict__ rel_idx,
    float* __restrict__ out,
    int n_edges)
{
    __shared__ float4 Wl[N_RELS * (N_HID / 4)];
    for (int i = threadIdx.x; i < N_RELS * (N_HID / 4); i += blockDim.x) {
        Wl[i] = reinterpret_cast<const float4*>(W)[i];
    }
    __syncthreads();

    const int sub = threadIdx.x & 15;
    const int group = threadIdx.x >> 4;
    const int groups_per_block = blockDim.x >> 4;
    const long stride = (long)gridDim.x * groups_per_block;
    const float4* __restrict__ h4 = reinterpret_cast<const float4*>(h);

    for (long e = (long)blockIdx.x * groups_per_block + group; e < n_edges; e += stride) {
        int s = src_idx[e], d = dst_idx[e], r = rel_idx[e];
        float4 u = h4[(long)s * 16 + sub];
        float4 v = h4[(long)d * 16 + sub];
        float4 w = Wl[r * 16 + sub];
        float p = u.x*w.x*v.x + u.y*w.y*v.y + u.z*w.z*v.z + u.w*w.w*v.w;
        p += __shfl_xor(p, 1, 64);
        p += __shfl_xor(p, 2, 64);
        p += __shfl_xor(p, 4, 64);
        p += __shfl_xor(p, 8, 64);
        if (sub == 0) out[e] = 1.0f / (1.0f + __expf(-p));
    }
}

extern "C" void kernel_launch(void* const* d_in, const int* in_sizes, int n_in,
                              void* d_out, int out_size, void* d_ws, size_t ws_size,
                              hipStream_t stream) {
    const float* h   = (const float*)d_in[0];
    const float* W   = (const float*)d_in[1];
    const int*   src = (const int*)d_in[2];
    const int*   dst = (const int*)d_in[3];
    const int*   rel = (const int*)d_in[4];
    float* out = (float*)d_out;

    const long n_h = in_sizes[0];          // 500000 * 64 floats
    const int n_edges = in_sizes[2];
    const size_t need = (size_t)n_h * sizeof(unsigned short);

    if (ws_size >= need) {
        unsigned short* hh = (unsigned short*)d_ws;

        // Pass 1: fp32 -> fp16, nontemporal fp32 reads (don't pollute L2 with
        // lines the gather will never reuse). 16 floats/thread/iter.
        cvt_fp16_kernel<<<4096, 256, 0, stream>>>(h, hh, n_h);

        // Pass 2: gather + dot + sigmoid. 128 edges/block, exact grid.
        const int block = 256;
        const int edges_per_block = (block / 8) * EPG;  // 128
        int grid = (n_edges + edges_per_block - 1) / edges_per_block;
        distmult_fp16_kernel<<<grid, block, 0, stream>>>(hh, W, src, dst, rel, out, n_edges);
    } else {
        const int block = 256;
        const int groups_per_block = block / 16;
        int blocks_needed = (n_edges + groups_per_block - 1) / groups_per_block;
        int grid = blocks_needed < 2048 ? blocks_needed : 2048;
        distmult_fp32_kernel<<<grid, block, 0, stream>>>(h, W, src, dst, rel, out, n_edges);
    }
}

// Round 5
// 105.332 us; speedup vs baseline: 1.1827x; 1.1827x over previous
//
#include <hip/hip_runtime.h>
#include <hip/hip_fp16.h>
#include <math.h>

#define N_RELS 10
#define N_HID 64

// ---------------- Kernel 1: h fp32 -> fp16 (RNE) into workspace ----------------
// Plain cached loads (nontemporal reads measured SLOWER: R4 post-mortem,
// cvt 27.6 -> 47 us). 8 floats/thread/iter, 2048 blocks: 27.6 us = streaming floor.
__global__ __launch_bounds__(256) void cvt_fp16_kernel(
    const float* __restrict__ h,
    unsigned short* __restrict__ hh,
    long n)  // n = total floats, multiple of 8
{
    long i = (long)blockIdx.x * blockDim.x + threadIdx.x;
    long stride = (long)gridDim.x * blockDim.x;
    const float4* __restrict__ h4 = reinterpret_cast<const float4*>(h);
    uint4* __restrict__ o4 = reinterpret_cast<uint4*>(hh);
    long n8 = n >> 3;
    for (long k = i; k < n8; k += stride) {
        float4 a = h4[2 * k];
        float4 b = h4[2 * k + 1];
        __half2 p0 = __floats2half2_rn(a.x, a.y);
        __half2 p1 = __floats2half2_rn(a.z, a.w);
        __half2 p2 = __floats2half2_rn(b.x, b.y);
        __half2 p3 = __floats2half2_rn(b.z, b.w);
        uint4 o;
        o.x = *reinterpret_cast<unsigned int*>(&p0);
        o.y = *reinterpret_cast<unsigned int*>(&p1);
        o.z = *reinterpret_cast<unsigned int*>(&p2);
        o.w = *reinterpret_cast<unsigned int*>(&p3);
        o4[k] = o;
    }
}

// ---------------- Kernel 2: gather fp16 rows, dot, sigmoid ----------------
// 8 lanes per edge: lane sub holds dims [sub*8, sub*8+8) as one uint4 (8 halves).
#define EPG 4
__global__ __launch_bounds__(256) void distmult_fp16_kernel(
    const unsigned short* __restrict__ hh,   // [N, 64] fp16
    const float* __restrict__ W,
    const int* __restrict__ src_idx,
    const int* __restrict__ dst_idx,
    const int* __restrict__ rel_idx,
    float* __restrict__ out,
    int n_edges)
{
    __shared__ float Wl[N_RELS * N_HID];
    for (int i = threadIdx.x; i < N_RELS * (N_HID / 4); i += blockDim.x) {
        reinterpret_cast<float4*>(Wl)[i] = reinterpret_cast<const float4*>(W)[i];
    }
    __syncthreads();

    const int sub = threadIdx.x & 7;          // lane within 8-lane edge group
    const int group = threadIdx.x >> 3;       // 32 groups per 256-thr block
    const int groups_per_block = blockDim.x >> 3;
    const long stride = (long)gridDim.x * groups_per_block * EPG;
    const uint4* __restrict__ h8 = reinterpret_cast<const uint4*>(hh); // 8 uint4 per row

    for (long base = ((long)blockIdx.x * groups_per_block + group) * EPG;
         base < n_edges; base += stride) {

        float p[EPG];

        if (base + EPG <= n_edges) {
            const int4 s4 = *reinterpret_cast<const int4*>(&src_idx[base]);
            const int4 d4 = *reinterpret_cast<const int4*>(&dst_idx[base]);
            const int4 r4 = *reinterpret_cast<const int4*>(&rel_idx[base]);

            // 8 independent 16B gathers in flight (4 src rows + 4 dst rows).
            const uint4 u0 = h8[(long)s4.x * 8 + sub];
            const uint4 u1 = h8[(long)s4.y * 8 + sub];
            const uint4 u2 = h8[(long)s4.z * 8 + sub];
            const uint4 u3 = h8[(long)s4.w * 8 + sub];
            const uint4 v0 = h8[(long)d4.x * 8 + sub];
            const uint4 v1 = h8[(long)d4.y * 8 + sub];
            const uint4 v2 = h8[(long)d4.z * 8 + sub];
            const uint4 v3 = h8[(long)d4.w * 8 + sub];

            const int rr[EPG] = {r4.x, r4.y, r4.z, r4.w};
            const uint4 uu[EPG] = {u0, u1, u2, u3};
            const uint4 vv[EPG] = {v0, v1, v2, v3};

            #pragma unroll
            for (int k = 0; k < EPG; ++k) {
                const float* wp = &Wl[rr[k] * N_HID + sub * 8];
                const __half2* up = reinterpret_cast<const __half2*>(&uu[k]);
                const __half2* vp = reinterpret_cast<const __half2*>(&vv[k]);
                float acc = 0.0f;
                #pragma unroll
                for (int j = 0; j < 4; ++j) {
                    float2 uf = __half22float2(up[j]);
                    float2 vf = __half22float2(vp[j]);
                    acc += uf.x * wp[2 * j] * vf.x;
                    acc += uf.y * wp[2 * j + 1] * vf.y;
                }
                p[k] = acc;
            }
        } else {
            #pragma unroll
            for (int k = 0; k < EPG; ++k) {
                long e = base + k;
                if (e < n_edges) {
                    int s = src_idx[e], d = dst_idx[e], r = rel_idx[e];
                    uint4 u = h8[(long)s * 8 + sub];
                    uint4 v = h8[(long)d * 8 + sub];
                    const float* wp = &Wl[r * N_HID + sub * 8];
                    const __half2* up = reinterpret_cast<const __half2*>(&u);
                    const __half2* vp = reinterpret_cast<const __half2*>(&v);
                    float acc = 0.0f;
                    #pragma unroll
                    for (int j = 0; j < 4; ++j) {
                        float2 uf = __half22float2(up[j]);
                        float2 vf = __half22float2(vp[j]);
                        acc += uf.x * wp[2 * j] * vf.x;
                        acc += uf.y * wp[2 * j + 1] * vf.y;
                    }
                    p[k] = acc;
                } else {
                    p[k] = 0.0f;
                }
            }
        }

        // Reduce across the 8-lane group (masks stay within the group).
        #pragma unroll
        for (int k = 0; k < EPG; ++k) {
            p[k] += __shfl_xor(p[k], 1, 64);
            p[k] += __shfl_xor(p[k], 2, 64);
            p[k] += __shfl_xor(p[k], 4, 64);
        }

        // Lanes 0..3 write 4 adjacent edges; out is never re-read -> nontemporal.
        if (sub < EPG) {
            long e = base + sub;
            if (e < n_edges) {
                float pv = p[sub];
                float sv = 1.0f / (1.0f + __expf(-pv));
                __builtin_nontemporal_store(sv, &out[e]);
            }
        }
    }
}

// ---------------- Fallback fp32 kernel (if workspace too small) ----------------
__global__ __launch_bounds__(256) void distmult_fp32_kernel(
    const float* __restrict__ h,
    const float* __restrict__ W,
    const int* __restrict__ src_idx,
    const int* __restrict__ dst_idx,
    const int* __restrict__ rel_idx,
    float* __restrict__ out,
    int n_edges)
{
    __shared__ float4 Wl[N_RELS * (N_HID / 4)];
    for (int i = threadIdx.x; i < N_RELS * (N_HID / 4); i += blockDim.x) {
        Wl[i] = reinterpret_cast<const float4*>(W)[i];
    }
    __syncthreads();

    const int sub = threadIdx.x & 15;
    const int group = threadIdx.x >> 4;
    const int groups_per_block = blockDim.x >> 4;
    const long stride = (long)gridDim.x * groups_per_block;
    const float4* __restrict__ h4 = reinterpret_cast<const float4*>(h);

    for (long e = (long)blockIdx.x * groups_per_block + group; e < n_edges; e += stride) {
        int s = src_idx[e], d = dst_idx[e], r = rel_idx[e];
        float4 u = h4[(long)s * 16 + sub];
        float4 v = h4[(long)d * 16 + sub];
        float4 w = Wl[r * 16 + sub];
        float p = u.x*w.x*v.x + u.y*w.y*v.y + u.z*w.z*v.z + u.w*w.w*v.w;
        p += __shfl_xor(p, 1, 64);
        p += __shfl_xor(p, 2, 64);
        p += __shfl_xor(p, 4, 64);
        p += __shfl_xor(p, 8, 64);
        if (sub == 0) out[e] = 1.0f / (1.0f + __expf(-p));
    }
}

extern "C" void kernel_launch(void* const* d_in, const int* in_sizes, int n_in,
                              void* d_out, int out_size, void* d_ws, size_t ws_size,
                              hipStream_t stream) {
    const float* h   = (const float*)d_in[0];
    const float* W   = (const float*)d_in[1];
    const int*   src = (const int*)d_in[2];
    const int*   dst = (const int*)d_in[3];
    const int*   rel = (const int*)d_in[4];
    float* out = (float*)d_out;

    const long n_h = in_sizes[0];          // 500000 * 64 floats
    const int n_edges = in_sizes[2];
    const size_t need = (size_t)n_h * sizeof(unsigned short);

    if (ws_size >= need) {
        unsigned short* hh = (unsigned short*)d_ws;

        // Pass 1: fp32 -> fp16 conversion (streaming floor ~27us at 2048 blocks).
        cvt_fp16_kernel<<<2048, 256, 0, stream>>>(h, hh, n_h);

        // Pass 2: gather + dot + sigmoid. 128 edges/block, exact grid.
        const int block = 256;
        const int edges_per_block = (block / 8) * EPG;  // 128
        int grid = (n_edges + edges_per_block - 1) / edges_per_block;
        distmult_fp16_kernel<<<grid, block, 0, stream>>>(hh, W, src, dst, rel, out, n_edges);
    } else {
        const int block = 256;
        const int groups_per_block = block / 16;
        int blocks_needed = (n_edges + groups_per_block - 1) / groups_per_block;
        int grid = blocks_needed < 2048 ? blocks_needed : 2048;
        distmult_fp32_kernel<<<grid, block, 0, stream>>>(h, W, src, dst, rel, out, n_edges);
    }
}